// Round 15
// baseline (216.216 us; speedup 1.0000x reference)
//
#include <hip/hip_runtime.h>

// EdgeConv fused pipeline, MI355X gfx950 — round 23.
// R22 post-mortem: fp8 stats landed numerically (absmax 0.0625) but gained
// only -1.3us — halving gathered BYTES did nothing. With R12 (more waves
// hurt) + R16 (more loads/wave spilled), the edge kernels are NOT byte-bound.
// Reframe: at VGPR 64/LDS 5KB the HW allows 32 waves/CU even under (256,4)
// (bound = allocator cap only), yet occupancy sat at 37-38% in EVERY config;
// R18's persistent 1024-block kernel hit 48.9%. 6250 blocks / 65us = ~96
// block-completions/us ~ CP dispatch throughput -> these short-block kernels
// are COMMAND-PROCESSOR dispatch-rate limited (resident = rate x lifetime).
// R23: double work per block, same per-wave shape: stats1+pass2 at 512
// threads / 8 waves / 32 nodes per block, grid 3125. Per-wave code
// byte-identical; ytile/btile -> 2048 floats; (512,4) = same 128-VGPR cap.
// Predict: occupancy 37 -> 55-75%, pass2 64.9 -> ~50, stats1 similar,
// total ~185-192. Tripwires: FETCH/WRITE blowup = spill -> revert;
// occupancy unchanged -> CP theory wrong -> latency floor, declare roofline.

#define N_NODES 100000
#define KE 16
#define E_EDGES (N_NODES * KE)
#define BN_EPS 1e-5f
#define NCHUNK32 (N_NODES / 32)   // 3125 32-node chunks (exact)
#define NTILES (N_NODES / 16)     // 6250 16-node GEMM tiles (exact)
#define GSLOTS 16

typedef __attribute__((ext_vector_type(8))) short bf16x8;  // 8 bf16 (4 VGPRs)
typedef __attribute__((ext_vector_type(4))) float f32x4;   // MFMA C/D
typedef __attribute__((ext_vector_type(4))) int i32x4;

#define MFMA(a, b, c) __builtin_amdgcn_mfma_f32_16x16x32_bf16((a), (b), (c), 0, 0, 0)
#define MFMA8(a, b, c) __builtin_amdgcn_mfma_f32_16x16x32_fp8_fp8((a), (b), (c), 0, 0, 0)

static __device__ __forceinline__ short bf16b(float f) {
  __bf16 h = (__bf16)f;  // RNE, hardware cvt on gfx950
  return __builtin_bit_cast(short, h);
}

#if __has_builtin(__builtin_amdgcn_cvt_pk_bf16_f32)
static __device__ __forceinline__ int pk2(float a, float b) {
  return __builtin_bit_cast(int, __builtin_amdgcn_cvt_pk_bf16_f32(a, b));
}
#else
static __device__ __forceinline__ int pk2(float a, float b) {
  return (int)(unsigned short)bf16b(a) | ((int)(unsigned short)bf16b(b) << 16);
}
#endif

// fp8 e4m3 (OCP) byte via HW cvt
static __device__ __forceinline__ unsigned char fp8b(float f) {
#if __has_builtin(__builtin_amdgcn_cvt_pk_fp8_f32)
  int p = __builtin_amdgcn_cvt_pk_fp8_f32(f, 0.f, 0, false);
  return (unsigned char)(p & 0xff);
#else
  union { float x; unsigned u; } v; v.x = f;
  unsigned s = (v.u >> 24) & 0x80;
  float af = fabsf(f);
  if (af < 1.953125e-3f) return (unsigned char)s;
  if (af > 448.f) af = 448.f;
  int e; float m = frexpf(af, &e);
  int exp = e + 6;
  int mant = (int)(m * 16.f + 0.5f) - 8;
  if (mant == 8) { mant = 0; exp++; }
  if (exp <= 0) return (unsigned char)s;
  if (exp > 15) { exp = 15; mant = 7; }
  return (unsigned char)(s | (exp << 3) | mant);
#endif
}

static __device__ __forceinline__ bf16x8 pack8(float4 a, float4 b) {
  i32x4 v = {pk2(a.x, a.y), pk2(a.z, a.w), pk2(b.x, b.y), pk2(b.z, b.w)};
  return __builtin_bit_cast(bf16x8, v);
}

static __device__ __forceinline__ bf16x8 pack8f(const float h[8]) {
  i32x4 v = {pk2(h[0], h[1]), pk2(h[2], h[3]), pk2(h[4], h[5]), pk2(h[6], h[7])};
  return __builtin_bit_cast(bf16x8, v);
}

static __device__ __forceinline__ float bf2f(short s) {
  unsigned u = ((unsigned)(unsigned short)s) << 16;
  return __builtin_bit_cast(float, u);
}

static __device__ __forceinline__ void stat_flush(float sacc[4], float qacc[4],
                                                  int quad, int n16, float* lstat) {
#pragma unroll
  for (int t = 0; t < 4; t++) {
    float s = sacc[t], q = qacc[t];
    s += __shfl_xor(s, 16); s += __shfl_xor(s, 32);
    q += __shfl_xor(q, 16); q += __shfl_xor(q, 32);
    if (quad == 0) {
      atomicAdd(&lstat[16 * t + n16], s);
      atomicAdd(&lstat[64 + 16 * t + n16], q);
    }
  }
}

// folded BN finalize: per-block recompute of bn coeffs from the 16-slot gacc
static __device__ __forceinline__ void bn_finalize(const float* __restrict__ gacc,
                                                   const float* __restrict__ g,
                                                   const float* __restrict__ be,
                                                   float* lbn, int tid) {
  if (tid < 64) {
    float s = 0.f, q = 0.f;
#pragma unroll
    for (int i = 0; i < GSLOTS; i++) {
      s += gacc[i * 128 + tid];
      q += gacc[i * 128 + 64 + tid];
    }
    float mean = s * (1.0f / E_EDGES);
    float var = q * (1.0f / E_EDGES) - mean * mean;  // biased, matches ref
    float rstd = rsqrtf(var + BN_EPS);
    float a = g[tid] * rstd;
    lbn[tid] = a;
    lbn[64 + tid] = be[tid] - mean * a;  // bn(v) = v*a + b
  }
}

// ---- node GEMMs + integrated prep ------------------------------------------
// Every block packs W1 frags into its own LDS; block 0 packs wp2 + zeroes
// gacc (stream-ordered for later kernels). Outputs: Ybf (bf16), Z (bf16,
// for pass2), Z8 (e4m3, stats-only gather copy).
__global__ __launch_bounds__(256) void k_nodeYZ(const float* __restrict__ x,
                                                const float* __restrict__ W1,
                                                const float* __restrict__ W2,
                                                short* __restrict__ wp2,
                                                float* __restrict__ gaccz,
                                                short* __restrict__ Ybf,
                                                short* __restrict__ Z,
                                                unsigned char* __restrict__ Z8) {
  __shared__ __align__(16) short wfl[8192];   // W1 B-frags (16 KB)
  int tid = threadIdx.x;
  for (int gsl = tid; gsl < 1024; gsl += 256) {  // pack W1 -> LDS (all blocks)
    int l = gsl & 63, st = gsl >> 6;
    int s = st >> 2, t = st & 3;
    int qq = l >> 4, nn = l & 15;
    for (int j = 0; j < 8; j++) {
      int k = 32 * s + qq * 8 + j, c = 16 * t + nn;
      float w = (s < 2) ? (W1[k * 64 + c] - W1[(k + 64) * 64 + c])
                        : W1[k * 64 + c];
      wfl[gsl * 8 + j] = bf16b(w);
    }
  }
  if (blockIdx.x == 0) {  // pack wp2 + zero gacc (for later kernels)
    for (int e = tid; e < 512; e += 256) {
      int l = e & 63, st = e >> 6;
      int s = st >> 2, t = st & 3;
      int qq = l >> 4, nn = l & 15;
      for (int j = 0; j < 8; j++) {
        int k = 32 * s + qq * 8 + j, c = 16 * t + nn;
        wp2[e * 8 + j] = bf16b(W2[k * 64 + c]);
      }
    }
    float4 zf = {0.f, 0.f, 0.f, 0.f};
    for (int i = 0; i < 4; i++)
      ((float4*)gaccz)[tid * 4 + i] = zf;   // 4096 floats = gacc1+gacc2
  }
  __syncthreads();
  int wave = tid >> 6, l = tid & 63, quad = l >> 4, n16 = l & 15;
  int tile = blockIdx.x * 4 + wave;
  if (tile >= NTILES) return;
  const bf16x8* wp1l = (const bf16x8*)wfl;
  const float* xr = x + (size_t)(tile * 16 + n16) * 64 + quad * 8;
  float4 x0 = *(const float4*)xr, x1 = *(const float4*)(xr + 4);
  float4 x2 = *(const float4*)(xr + 32), x3 = *(const float4*)(xr + 36);
  bf16x8 a0 = pack8(x0, x1);   // A[m=n16][k = quad*8+j]       (ch 0..31)
  bf16x8 a1 = pack8(x2, x3);   // A[m=n16][k = 32+quad*8+j]    (ch 32..63)
  f32x4 zero = {0.f, 0.f, 0.f, 0.f};
#pragma unroll
  for (int t = 0; t < 4; t++) {
    f32x4 y = MFMA(a0, wp1l[(0 + t) * 64 + l], zero);
    y = MFMA(a1, wp1l[(4 + t) * 64 + l], y);
    f32x4 z = MFMA(a0, wp1l[(8 + t) * 64 + l], zero);
    z = MFMA(a1, wp1l[(12 + t) * 64 + l], z);
#pragma unroll
    for (int r = 0; r < 4; r++) {  // D: row = quad*4+r, col = 16t+n16
      size_t row = (size_t)(tile * 16 + quad * 4 + r);
      Ybf[row * 64 + 16 * t + n16] = bf16b(y[r]);
      Z[row * 64 + 16 * t + n16] = bf16b(z[r]);
      Z8[row * 64 + 16 * t + n16] = fp8b(z[r]);
    }
  }
}

// ---- pass 1': BN1 stats, 512 threads / 8 waves / 32 nodes per block --------
// fp8 gather of Z8 + fp8-MFMA identity-transpose (R22). Per-wave shape
// identical to R22 (4 nodes/wave); p = wave*4+v in 0..31.
__global__ __launch_bounds__(512, 4) void k_stats1(const unsigned char* __restrict__ Z8,
                                                   const short* __restrict__ Ybf,
                                                   const int* __restrict__ ecol,
                                                   float* __restrict__ gacc) {
  __shared__ float lstat[128];
  __shared__ float ytile[2048];   // 32 nodes x 64 ch (f32, filled from bf16)
  int tid = threadIdx.x;
  if (tid < 128) lstat[tid] = 0.f;
  int nb = blockIdx.x * 32;
  {
    ushort4 yv = ((const ushort4*)(Ybf + (size_t)nb * 64))[tid];  // 512*4=2048
    ytile[tid * 4 + 0] = bf2f((short)yv.x);
    ytile[tid * 4 + 1] = bf2f((short)yv.y);
    ytile[tid * 4 + 2] = bf2f((short)yv.z);
    ytile[tid * 4 + 3] = bf2f((short)yv.w);
  }
  int wave = tid >> 6, l = tid & 63, quad = l >> 4, n16 = l & 15;
  int idx[4];
#pragma unroll
  for (int v = 0; v < 4; v++)
    idx[v] = ecol[nb * KE + (wave * 4 + v) * 16 + n16];
  long z8a[4], z8b[4];
#pragma unroll
  for (int v = 0; v < 4; v++) {
    const unsigned char* pz = Z8 + (size_t)idx[v] * 64 + quad * 8;
    z8a[v] = *(const long*)pz;          // ch quad*8 .. +7
    z8b[v] = *(const long*)(pz + 32);   // ch 32+quad*8 .. +7
  }
  // identity B-frags in e4m3: byte j of lane (quad,n16) is B[k=quad*8+j][n16]
  long e0 = 0, e1 = 0;
  {
    int b0 = n16 - quad * 8;
    if (b0 >= 0 && b0 < 8) e0 = 0x38L << (8 * b0);
    int b1 = n16 + 16 - quad * 8;
    if (b1 >= 0 && b1 < 8) e1 = 0x38L << (8 * b1);
  }
  __syncthreads();
  f32x4 zero = {0.f, 0.f, 0.f, 0.f};
  float sacc[4] = {0.f, 0.f, 0.f, 0.f}, qacc[4] = {0.f, 0.f, 0.f, 0.f};
#pragma unroll
  for (int v = 0; v < 4; v++) {
    int p = wave * 4 + v;
    f32x4 d[4];
    d[0] = MFMA8(z8a[v], e0, zero);   // channels  0..15 (col n16)
    d[1] = MFMA8(z8a[v], e1, zero);   // channels 16..31
    d[2] = MFMA8(z8b[v], e0, zero);   // channels 32..47
    d[3] = MFMA8(z8b[v], e1, zero);   // channels 48..63
#pragma unroll
    for (int t = 0; t < 4; t++) {
      float yv = ytile[p * 64 + 16 * t + n16];
#pragma unroll
      for (int r = 0; r < 4; r++) {
        float h = d[t][r] + yv;
        sacc[t] += h;
        qacc[t] = fmaf(h, h, qacc[t]);
      }
    }
  }
  stat_flush(sacc, qacc, quad, n16, lstat);
  __syncthreads();
  if (tid < 128)
    atomicAdd(&gacc[(blockIdx.x & (GSLOTS - 1)) * 128 + tid], lstat[tid]);
}

// ---- pass 2': 512 threads / 8 waves / 32 nodes per block -------------------
// gather Z -> in-register BN1/ReLU -> GEMM2 + stats2 + minmax. Per-wave
// shape identical to R21 (proven 65us config); split hmax/hmin stores.
__global__ __launch_bounds__(512, 4) void k_pass2(const short* __restrict__ Z,
                                                  const short* __restrict__ Ybf,
                                                  const int* __restrict__ ecol,
                                                  const bf16x8* __restrict__ wp2,
                                                  const float* __restrict__ gacc1,
                                                  const float* __restrict__ g1,
                                                  const float* __restrict__ be1,
                                                  float* __restrict__ gacc,
                                                  short* __restrict__ hmax,
                                                  short* __restrict__ hmin) {
  __shared__ float lstat[128];
  __shared__ float lbn[128];
  __shared__ float btile[2048];   // bias: a_c*Y[i][c] + b_c, 32 nodes x 64 ch
  int tid = threadIdx.x;
  if (tid < 128) lstat[tid] = 0.f;
  bn_finalize(gacc1, g1, be1, lbn, tid);
  int nb = blockIdx.x * 32;
  int wave = tid >> 6, l = tid & 63, quad = l >> 4, n16 = l & 15;
  int idx[4];
#pragma unroll
  for (int v = 0; v < 4; v++)
    idx[v] = ecol[nb * KE + (wave * 4 + v) * 16 + n16];
  bf16x8 zf0[4], zf1[4];
#pragma unroll
  for (int v = 0; v < 4; v++) {
    const short* pz = Z + (size_t)idx[v] * 64 + quad * 8;
    zf0[v] = *(const bf16x8*)pz;
    zf1[v] = *(const bf16x8*)(pz + 32);
  }
  bf16x8 wf2[8];
#pragma unroll
  for (int u = 0; u < 8; u++) wf2[u] = wp2[u * 64 + l];
  __syncthreads();                       // lbn ready
  {                                      // bias tile: one ushort4 per thread
    ushort4 yv = ((const ushort4*)(Ybf + (size_t)nb * 64))[tid];  // 512*4=2048
    int c0 = (tid * 4) & 63;
    btile[tid * 4 + 0] = fmaf(lbn[c0 + 0], bf2f((short)yv.x), lbn[64 + c0 + 0]);
    btile[tid * 4 + 1] = fmaf(lbn[c0 + 1], bf2f((short)yv.y), lbn[64 + c0 + 1]);
    btile[tid * 4 + 2] = fmaf(lbn[c0 + 2], bf2f((short)yv.z), lbn[64 + c0 + 2]);
    btile[tid * 4 + 3] = fmaf(lbn[c0 + 3], bf2f((short)yv.w), lbn[64 + c0 + 3]);
  }
  __syncthreads();                       // btile ready
  float ac0[8], ac1[8];
#pragma unroll
  for (int j = 0; j < 8; j++) {
    ac0[j] = lbn[quad * 8 + j];
    ac1[j] = lbn[32 + quad * 8 + j];
  }
  float sacc[4] = {0.f, 0.f, 0.f, 0.f}, qacc[4] = {0.f, 0.f, 0.f, 0.f};
#pragma unroll
  for (int v = 0; v < 4; v++) {
    int p = wave * 4 + v;
    const float* bb = &btile[p * 64 + quad * 8];
    float h0[8], h1[8];
#pragma unroll
    for (int j = 0; j < 8; j++) {
      h0[j] = fmaxf(fmaf(ac0[j], bf2f(zf0[v][j]), bb[j]), 0.f);
      h1[j] = fmaxf(fmaf(ac1[j], bf2f(zf1[v][j]), bb[32 + j]), 0.f);
    }
    bf16x8 f0 = pack8f(h0), f1 = pack8f(h1);
    f32x4 acc2[4];
#pragma unroll
    for (int t = 0; t < 4; t++) {
      f32x4 a = {0.f, 0.f, 0.f, 0.f};
      a = MFMA(f0, wf2[0 + t], a);
      a = MFMA(f1, wf2[4 + t], a);
      acc2[t] = a;
    }
#pragma unroll
    for (int t = 0; t < 4; t++) {
      sacc[t] += (acc2[t][0] + acc2[t][1]) + (acc2[t][2] + acc2[t][3]);
      qacc[t] = fmaf(acc2[t][0], acc2[t][0],
                fmaf(acc2[t][1], acc2[t][1],
                fmaf(acc2[t][2], acc2[t][2],
                fmaf(acc2[t][3], acc2[t][3], qacc[t]))));
    }
    // per-node, per-channel max & min of h2_pre over the 16 edges
    float vmx[4], vmn[4];
#pragma unroll
    for (int t = 0; t < 4; t++) {
      float mx = fmaxf(fmaxf(acc2[t][0], acc2[t][1]), fmaxf(acc2[t][2], acc2[t][3]));
      float mn = fminf(fminf(acc2[t][0], acc2[t][1]), fminf(acc2[t][2], acc2[t][3]));
      mx = fmaxf(mx, __shfl_xor(mx, 16)); mx = fmaxf(mx, __shfl_xor(mx, 32));
      mn = fminf(mn, __shfl_xor(mn, 16)); mn = fminf(mn, __shfl_xor(mn, 32));
      vmx[t] = mx; vmn[t] = mn;
    }
    int n = nb + p;
    float ox = (quad == 0) ? vmx[0] : (quad == 1) ? vmx[1] : (quad == 2) ? vmx[2] : vmx[3];
    float on = (quad == 0) ? vmn[0] : (quad == 1) ? vmn[1] : (quad == 2) ? vmn[2] : vmn[3];
    hmax[(size_t)n * 64 + l] = bf16b(ox);  // lane l == channel l: coalesced
    hmin[(size_t)n * 64 + l] = bf16b(on);
  }
  stat_flush(sacc, qacc, quad, n16, lstat);
  __syncthreads();
  if (tid < 128)
    atomicAdd(&gacc[(blockIdx.x & (GSLOTS - 1)) * 128 + tid], lstat[tid]);
}

// ---- pass 3: folded finalize2 + elementwise BN2/ReLU + min/max select ------
// max_m relu(a*h+b) = relu(a>=0 ? a*hmax+b : a*hmin+b)  (affine+relu monotone)
__global__ __launch_bounds__(256) void k_pass3(const short* __restrict__ hmax,
                                               const short* __restrict__ hmin,
                                               const float* __restrict__ gacc2,
                                               const float* __restrict__ g2,
                                               const float* __restrict__ be2,
                                               float* __restrict__ out) {
  __shared__ float lbn[128];
  int tid = threadIdx.x;
  bn_finalize(gacc2, g2, be2, lbn, tid);  // folded finalize2
  __syncthreads();
  int g = blockIdx.x * 256 + tid;  // 1.6M threads, 4 channels each
  int base = g * 4;
  int c4 = base & 63;
  short4 mx4 = *(const short4*)(hmax + base);
  short4 mn4 = *(const short4*)(hmin + base);
  float4 a4 = *(const float4*)(&lbn[c4]);
  float4 b4 = *(const float4*)(&lbn[64 + c4]);
  float4 o;
  o.x = fmaxf(a4.x >= 0.f ? fmaf(a4.x, bf2f(mx4.x), b4.x) : fmaf(a4.x, bf2f(mn4.x), b4.x), 0.f);
  o.y = fmaxf(a4.y >= 0.f ? fmaf(a4.y, bf2f(mx4.y), b4.y) : fmaf(a4.y, bf2f(mn4.y), b4.y), 0.f);
  o.z = fmaxf(a4.z >= 0.f ? fmaf(a4.z, bf2f(mx4.z), b4.z) : fmaf(a4.z, bf2f(mn4.z), b4.z), 0.f);
  o.w = fmaxf(a4.w >= 0.f ? fmaf(a4.w, bf2f(mx4.w), b4.w) : fmaf(a4.w, bf2f(mn4.w), b4.w), 0.f);
  *(float4*)(out + base) = o;
}

extern "C" void kernel_launch(void* const* d_in, const int* in_sizes, int n_in,
                              void* d_out, int out_size, void* d_ws, size_t ws_size,
                              hipStream_t stream) {
  const float* x   = (const float*)d_in[0];
  // d_in[1] = edge_row: structurally repeat(arange(N),16), unused
  const int*   ec  = (const int*)d_in[2];
  const float* W1  = (const float*)d_in[3];
  // d_in[4] = b1: cancels in BN, unused
  const float* g1  = (const float*)d_in[5];
  const float* be1 = (const float*)d_in[6];
  const float* W2  = (const float*)d_in[7];
  // d_in[8] = b2: cancels in BN, unused
  const float* g2  = (const float*)d_in[9];
  const float* be2 = (const float*)d_in[10];
  float* out = (float*)d_out;

  char* ws = (char*)d_ws;
  short* wp2s  = (short*)(ws + 16384);          // 8 KB packed W2
  float* gacc1 = (float*)(ws + 24576);          // 16 slots x 128 = 8 KB
  float* gacc2 = (float*)(ws + 32768);          // 8 KB (contiguous w/ gacc1)
  short* Ybf   = (short*)(ws + 98304);          // Y = X@Wd bf16: 12.8 MB
  short* Zb    = (short*)(ws + 98304 + 12800000);           // Z bf16: 12.8 MB
  short* hmax  = (short*)(ws + 98304 + 2 * 12800000);       // 12.8 MB
  short* hmin  = (short*)(ws + 98304 + 3 * 12800000);       // 12.8 MB
  unsigned char* Z8 = (unsigned char*)(ws + 98304 + 4 * 12800000);  // 6.4 MB

  hipLaunchKernelGGL(k_nodeYZ, dim3((NTILES + 3) / 4), dim3(256), 0, stream,
                     x, W1, W2, wp2s, gacc1, Ybf, Zb, Z8);
  hipLaunchKernelGGL(k_stats1, dim3(NCHUNK32), dim3(512), 0, stream,
                     Z8, Ybf, ec, gacc1);
  hipLaunchKernelGGL(k_pass2, dim3(NCHUNK32), dim3(512), 0, stream,
                     Zb, Ybf, ec, (const bf16x8*)wp2s, gacc1, g1, be1,
                     gacc2, hmax, hmin);
  hipLaunchKernelGGL(k_pass3, dim3(6250), dim3(256), 0, stream,
                     hmax, hmin, gacc2, g2, be2, out);
}

// Round 16
// 206.457 us; speedup vs baseline: 1.0473x; 1.0473x over previous
//
#include <hip/hip_runtime.h>

// EdgeConv fused pipeline, MI355X gfx950 — round 24 (revert to R22 = best).
// R23 post-mortem: 512-thread blocks REFUTED the CP-dispatch theory —
// occupancy still 37.5% (pre-committed tripwire) and pass2 regressed
// 64.9->72.2us. Occupancy ledger complete: ~12 waves/CU in EVERY config;
// every lever (wave slots R12/R14, MLP R16, bytes R22, block shape R23)
// neutral-or-negative. Edge kernels sit at a latency-chain equilibrium no
// available knob moves. R24 = byte-exact R22 (206.8us measured): 256-thread
// edge kernels, fp8 stats gather, bf16 Y, split hmax/hmin stores. If this
// reproduces ~207us, next round declares roofline.

#define N_NODES 100000
#define KE 16
#define E_EDGES (N_NODES * KE)
#define BN_EPS 1e-5f
#define NCHUNK (N_NODES / KE)      // 6250 16-node chunks (exact)
#define NTILES (N_NODES / 16)      // 6250 16-node GEMM tiles (exact)
#define GSLOTS 16

typedef __attribute__((ext_vector_type(8))) short bf16x8;  // 8 bf16 (4 VGPRs)
typedef __attribute__((ext_vector_type(4))) float f32x4;   // MFMA C/D
typedef __attribute__((ext_vector_type(4))) int i32x4;

#define MFMA(a, b, c) __builtin_amdgcn_mfma_f32_16x16x32_bf16((a), (b), (c), 0, 0, 0)
#define MFMA8(a, b, c) __builtin_amdgcn_mfma_f32_16x16x32_fp8_fp8((a), (b), (c), 0, 0, 0)

static __device__ __forceinline__ short bf16b(float f) {
  __bf16 h = (__bf16)f;  // RNE, hardware cvt on gfx950
  return __builtin_bit_cast(short, h);
}

#if __has_builtin(__builtin_amdgcn_cvt_pk_bf16_f32)
static __device__ __forceinline__ int pk2(float a, float b) {
  return __builtin_bit_cast(int, __builtin_amdgcn_cvt_pk_bf16_f32(a, b));
}
#else
static __device__ __forceinline__ int pk2(float a, float b) {
  return (int)(unsigned short)bf16b(a) | ((int)(unsigned short)bf16b(b) << 16);
}
#endif

// fp8 e4m3 (OCP) byte via HW cvt
static __device__ __forceinline__ unsigned char fp8b(float f) {
#if __has_builtin(__builtin_amdgcn_cvt_pk_fp8_f32)
  int p = __builtin_amdgcn_cvt_pk_fp8_f32(f, 0.f, 0, false);
  return (unsigned char)(p & 0xff);
#else
  union { float x; unsigned u; } v; v.x = f;
  unsigned s = (v.u >> 24) & 0x80;
  float af = fabsf(f);
  if (af < 1.953125e-3f) return (unsigned char)s;
  if (af > 448.f) af = 448.f;
  int e; float m = frexpf(af, &e);
  int exp = e + 6;
  int mant = (int)(m * 16.f + 0.5f) - 8;
  if (mant == 8) { mant = 0; exp++; }
  if (exp <= 0) return (unsigned char)s;
  if (exp > 15) { exp = 15; mant = 7; }
  return (unsigned char)(s | (exp << 3) | mant);
#endif
}

static __device__ __forceinline__ bf16x8 pack8(float4 a, float4 b) {
  i32x4 v = {pk2(a.x, a.y), pk2(a.z, a.w), pk2(b.x, b.y), pk2(b.z, b.w)};
  return __builtin_bit_cast(bf16x8, v);
}

static __device__ __forceinline__ bf16x8 pack8f(const float h[8]) {
  i32x4 v = {pk2(h[0], h[1]), pk2(h[2], h[3]), pk2(h[4], h[5]), pk2(h[6], h[7])};
  return __builtin_bit_cast(bf16x8, v);
}

static __device__ __forceinline__ float bf2f(short s) {
  unsigned u = ((unsigned)(unsigned short)s) << 16;
  return __builtin_bit_cast(float, u);
}

static __device__ __forceinline__ void stat_flush(float sacc[4], float qacc[4],
                                                  int quad, int n16, float* lstat) {
#pragma unroll
  for (int t = 0; t < 4; t++) {
    float s = sacc[t], q = qacc[t];
    s += __shfl_xor(s, 16); s += __shfl_xor(s, 32);
    q += __shfl_xor(q, 16); q += __shfl_xor(q, 32);
    if (quad == 0) {
      atomicAdd(&lstat[16 * t + n16], s);
      atomicAdd(&lstat[64 + 16 * t + n16], q);
    }
  }
}

// folded BN finalize: per-block recompute of bn coeffs from the 16-slot gacc
static __device__ __forceinline__ void bn_finalize(const float* __restrict__ gacc,
                                                   const float* __restrict__ g,
                                                   const float* __restrict__ be,
                                                   float* lbn, int tid) {
  if (tid < 64) {
    float s = 0.f, q = 0.f;
#pragma unroll
    for (int i = 0; i < GSLOTS; i++) {
      s += gacc[i * 128 + tid];
      q += gacc[i * 128 + 64 + tid];
    }
    float mean = s * (1.0f / E_EDGES);
    float var = q * (1.0f / E_EDGES) - mean * mean;  // biased, matches ref
    float rstd = rsqrtf(var + BN_EPS);
    float a = g[tid] * rstd;
    lbn[tid] = a;
    lbn[64 + tid] = be[tid] - mean * a;  // bn(v) = v*a + b
  }
}

// ---- node GEMMs + integrated prep ------------------------------------------
// Every block packs W1 frags into its own LDS; block 0 packs wp2 + zeroes
// gacc (stream-ordered for later kernels). Outputs: Ybf (bf16), Z (bf16,
// for pass2), Z8 (e4m3, stats-only gather copy).
__global__ __launch_bounds__(256) void k_nodeYZ(const float* __restrict__ x,
                                                const float* __restrict__ W1,
                                                const float* __restrict__ W2,
                                                short* __restrict__ wp2,
                                                float* __restrict__ gaccz,
                                                short* __restrict__ Ybf,
                                                short* __restrict__ Z,
                                                unsigned char* __restrict__ Z8) {
  __shared__ __align__(16) short wfl[8192];   // W1 B-frags (16 KB)
  int tid = threadIdx.x;
  for (int gsl = tid; gsl < 1024; gsl += 256) {  // pack W1 -> LDS (all blocks)
    int l = gsl & 63, st = gsl >> 6;
    int s = st >> 2, t = st & 3;
    int qq = l >> 4, nn = l & 15;
    for (int j = 0; j < 8; j++) {
      int k = 32 * s + qq * 8 + j, c = 16 * t + nn;
      float w = (s < 2) ? (W1[k * 64 + c] - W1[(k + 64) * 64 + c])
                        : W1[k * 64 + c];
      wfl[gsl * 8 + j] = bf16b(w);
    }
  }
  if (blockIdx.x == 0) {  // pack wp2 + zero gacc (for later kernels)
    for (int e = tid; e < 512; e += 256) {
      int l = e & 63, st = e >> 6;
      int s = st >> 2, t = st & 3;
      int qq = l >> 4, nn = l & 15;
      for (int j = 0; j < 8; j++) {
        int k = 32 * s + qq * 8 + j, c = 16 * t + nn;
        wp2[e * 8 + j] = bf16b(W2[k * 64 + c]);
      }
    }
    float4 zf = {0.f, 0.f, 0.f, 0.f};
    for (int i = 0; i < 4; i++)
      ((float4*)gaccz)[tid * 4 + i] = zf;   // 4096 floats = gacc1+gacc2
  }
  __syncthreads();
  int wave = tid >> 6, l = tid & 63, quad = l >> 4, n16 = l & 15;
  int tile = blockIdx.x * 4 + wave;
  if (tile >= NTILES) return;
  const bf16x8* wp1l = (const bf16x8*)wfl;
  const float* xr = x + (size_t)(tile * 16 + n16) * 64 + quad * 8;
  float4 x0 = *(const float4*)xr, x1 = *(const float4*)(xr + 4);
  float4 x2 = *(const float4*)(xr + 32), x3 = *(const float4*)(xr + 36);
  bf16x8 a0 = pack8(x0, x1);   // A[m=n16][k = quad*8+j]       (ch 0..31)
  bf16x8 a1 = pack8(x2, x3);   // A[m=n16][k = 32+quad*8+j]    (ch 32..63)
  f32x4 zero = {0.f, 0.f, 0.f, 0.f};
#pragma unroll
  for (int t = 0; t < 4; t++) {
    f32x4 y = MFMA(a0, wp1l[(0 + t) * 64 + l], zero);
    y = MFMA(a1, wp1l[(4 + t) * 64 + l], y);
    f32x4 z = MFMA(a0, wp1l[(8 + t) * 64 + l], zero);
    z = MFMA(a1, wp1l[(12 + t) * 64 + l], z);
#pragma unroll
    for (int r = 0; r < 4; r++) {  // D: row = quad*4+r, col = 16t+n16
      size_t row = (size_t)(tile * 16 + quad * 4 + r);
      Ybf[row * 64 + 16 * t + n16] = bf16b(y[r]);
      Z[row * 64 + 16 * t + n16] = bf16b(z[r]);
      Z8[row * 64 + 16 * t + n16] = fp8b(z[r]);
    }
  }
}

// ---- pass 1': BN1 stats via fp8 gather of Z8 + fp8-MFMA identity-transpose -
// Lane (quad,n16), edge v: loads 8B at Z8[idx][quad*8] and +32 (k=quad*8+j).
// e0[k][n]=delta(k,n), e1[k][n]=delta(k,16+n) as packed e4m3 bytes (0x38=1.0).
// D layout (dtype-independent): col=n16 -> channel, row=quad*4+r -> edge.
// h = D[r] + Y[p][c]; edge-reduce = stat_flush (2 shfl per t).
__global__ __launch_bounds__(256, 4) void k_stats1(const unsigned char* __restrict__ Z8,
                                                   const short* __restrict__ Ybf,
                                                   const int* __restrict__ ecol,
                                                   float* __restrict__ gacc) {
  __shared__ float lstat[128];
  __shared__ float ytile[1024];   // 16 nodes x 64 ch (f32, filled from bf16)
  int tid = threadIdx.x;
  if (tid < 128) lstat[tid] = 0.f;
  int nb = blockIdx.x * 16;
  {
    ushort4 yv = ((const ushort4*)(Ybf + (size_t)nb * 64))[tid];  // 4 elems
    ytile[tid * 4 + 0] = bf2f((short)yv.x);
    ytile[tid * 4 + 1] = bf2f((short)yv.y);
    ytile[tid * 4 + 2] = bf2f((short)yv.z);
    ytile[tid * 4 + 3] = bf2f((short)yv.w);
  }
  int wave = tid >> 6, l = tid & 63, quad = l >> 4, n16 = l & 15;
  int idx[4];
#pragma unroll
  for (int v = 0; v < 4; v++)
    idx[v] = ecol[nb * KE + (wave * 4 + v) * 16 + n16];
  long z8a[4], z8b[4];
#pragma unroll
  for (int v = 0; v < 4; v++) {
    const unsigned char* pz = Z8 + (size_t)idx[v] * 64 + quad * 8;
    z8a[v] = *(const long*)pz;          // ch quad*8 .. +7
    z8b[v] = *(const long*)(pz + 32);   // ch 32+quad*8 .. +7
  }
  // identity B-frags in e4m3: byte j of lane (quad,n16) is B[k=quad*8+j][n16]
  long e0 = 0, e1 = 0;
  {
    int b0 = n16 - quad * 8;
    if (b0 >= 0 && b0 < 8) e0 = 0x38L << (8 * b0);
    int b1 = n16 + 16 - quad * 8;
    if (b1 >= 0 && b1 < 8) e1 = 0x38L << (8 * b1);
  }
  __syncthreads();
  f32x4 zero = {0.f, 0.f, 0.f, 0.f};
  float sacc[4] = {0.f, 0.f, 0.f, 0.f}, qacc[4] = {0.f, 0.f, 0.f, 0.f};
#pragma unroll
  for (int v = 0; v < 4; v++) {
    int p = wave * 4 + v;
    f32x4 d[4];
    d[0] = MFMA8(z8a[v], e0, zero);   // channels  0..15 (col n16)
    d[1] = MFMA8(z8a[v], e1, zero);   // channels 16..31
    d[2] = MFMA8(z8b[v], e0, zero);   // channels 32..47
    d[3] = MFMA8(z8b[v], e1, zero);   // channels 48..63
#pragma unroll
    for (int t = 0; t < 4; t++) {
      float yv = ytile[p * 64 + 16 * t + n16];
#pragma unroll
      for (int r = 0; r < 4; r++) {
        float h = d[t][r] + yv;
        sacc[t] += h;
        qacc[t] = fmaf(h, h, qacc[t]);
      }
    }
  }
  stat_flush(sacc, qacc, quad, n16, lstat);
  __syncthreads();
  if (tid < 128)
    atomicAdd(&gacc[(blockIdx.x & (GSLOTS - 1)) * 128 + tid], lstat[tid]);
}

// ---- pass 2': gather Z -> in-register BN1/ReLU -> GEMM2 + stats2 + minmax --
// A-frag built directly: lane l holds relu(a_c*Z[j][c] + B[i][c]) for
// edge m=l&15, channels c=(l>>4)*8+j — no LDS transpose tile, no GEMM1.
// (256,4): cap 128, natural VGPR 64 -> proven 64.7us config (R22).
__global__ __launch_bounds__(256, 4) void k_pass2(const short* __restrict__ Z,
                                                  const short* __restrict__ Ybf,
                                                  const int* __restrict__ ecol,
                                                  const bf16x8* __restrict__ wp2,
                                                  const float* __restrict__ gacc1,
                                                  const float* __restrict__ g1,
                                                  const float* __restrict__ be1,
                                                  float* __restrict__ gacc,
                                                  short* __restrict__ hmax,
                                                  short* __restrict__ hmin) {
  __shared__ float lstat[128];
  __shared__ float lbn[128];
  __shared__ float btile[1024];   // bias: a_c*Y[i][c] + b_c, 16 nodes x 64 ch
  int tid = threadIdx.x;
  if (tid < 128) lstat[tid] = 0.f;
  bn_finalize(gacc1, g1, be1, lbn, tid);
  int nb = blockIdx.x * 16;
  int wave = tid >> 6, l = tid & 63, quad = l >> 4, n16 = l & 15;
  int idx[4];
#pragma unroll
  for (int v = 0; v < 4; v++)
    idx[v] = ecol[nb * KE + (wave * 4 + v) * 16 + n16];
  bf16x8 zf0[4], zf1[4];
#pragma unroll
  for (int v = 0; v < 4; v++) {
    const short* pz = Z + (size_t)idx[v] * 64 + quad * 8;
    zf0[v] = *(const bf16x8*)pz;
    zf1[v] = *(const bf16x8*)(pz + 32);
  }
  bf16x8 wf2[8];
#pragma unroll
  for (int u = 0; u < 8; u++) wf2[u] = wp2[u * 64 + l];
  __syncthreads();                       // lbn ready
  {                                      // bias tile: one ushort4 per thread
    ushort4 yv = ((const ushort4*)(Ybf + (size_t)nb * 64))[tid];
    int c0 = (tid * 4) & 63;
    btile[tid * 4 + 0] = fmaf(lbn[c0 + 0], bf2f((short)yv.x), lbn[64 + c0 + 0]);
    btile[tid * 4 + 1] = fmaf(lbn[c0 + 1], bf2f((short)yv.y), lbn[64 + c0 + 1]);
    btile[tid * 4 + 2] = fmaf(lbn[c0 + 2], bf2f((short)yv.z), lbn[64 + c0 + 2]);
    btile[tid * 4 + 3] = fmaf(lbn[c0 + 3], bf2f((short)yv.w), lbn[64 + c0 + 3]);
  }
  __syncthreads();                       // btile ready
  float ac0[8], ac1[8];
#pragma unroll
  for (int j = 0; j < 8; j++) {
    ac0[j] = lbn[quad * 8 + j];
    ac1[j] = lbn[32 + quad * 8 + j];
  }
  float sacc[4] = {0.f, 0.f, 0.f, 0.f}, qacc[4] = {0.f, 0.f, 0.f, 0.f};
#pragma unroll
  for (int v = 0; v < 4; v++) {
    int p = wave * 4 + v;
    const float* bb = &btile[p * 64 + quad * 8];
    float h0[8], h1[8];
#pragma unroll
    for (int j = 0; j < 8; j++) {
      h0[j] = fmaxf(fmaf(ac0[j], bf2f(zf0[v][j]), bb[j]), 0.f);
      h1[j] = fmaxf(fmaf(ac1[j], bf2f(zf1[v][j]), bb[32 + j]), 0.f);
    }
    bf16x8 f0 = pack8f(h0), f1 = pack8f(h1);
    f32x4 acc2[4];
#pragma unroll
    for (int t = 0; t < 4; t++) {
      f32x4 a = {0.f, 0.f, 0.f, 0.f};
      a = MFMA(f0, wf2[0 + t], a);
      a = MFMA(f1, wf2[4 + t], a);
      acc2[t] = a;
    }
#pragma unroll
    for (int t = 0; t < 4; t++) {
      sacc[t] += (acc2[t][0] + acc2[t][1]) + (acc2[t][2] + acc2[t][3]);
      qacc[t] = fmaf(acc2[t][0], acc2[t][0],
                fmaf(acc2[t][1], acc2[t][1],
                fmaf(acc2[t][2], acc2[t][2],
                fmaf(acc2[t][3], acc2[t][3], qacc[t]))));
    }
    // per-node, per-channel max & min of h2_pre over the 16 edges
    float vmx[4], vmn[4];
#pragma unroll
    for (int t = 0; t < 4; t++) {
      float mx = fmaxf(fmaxf(acc2[t][0], acc2[t][1]), fmaxf(acc2[t][2], acc2[t][3]));
      float mn = fminf(fminf(acc2[t][0], acc2[t][1]), fminf(acc2[t][2], acc2[t][3]));
      mx = fmaxf(mx, __shfl_xor(mx, 16)); mx = fmaxf(mx, __shfl_xor(mx, 32));
      mn = fminf(mn, __shfl_xor(mn, 16)); mn = fminf(mn, __shfl_xor(mn, 32));
      vmx[t] = mx; vmn[t] = mn;
    }
    int n = nb + p;
    float ox = (quad == 0) ? vmx[0] : (quad == 1) ? vmx[1] : (quad == 2) ? vmx[2] : vmx[3];
    float on = (quad == 0) ? vmn[0] : (quad == 1) ? vmn[1] : (quad == 2) ? vmn[2] : vmn[3];
    hmax[(size_t)n * 64 + l] = bf16b(ox);  // lane l == channel l: coalesced
    hmin[(size_t)n * 64 + l] = bf16b(on);
  }
  stat_flush(sacc, qacc, quad, n16, lstat);
  __syncthreads();
  if (tid < 128)
    atomicAdd(&gacc[(blockIdx.x & (GSLOTS - 1)) * 128 + tid], lstat[tid]);
}

// ---- pass 3: folded finalize2 + elementwise BN2/ReLU + min/max select ------
// max_m relu(a*h+b) = relu(a>=0 ? a*hmax+b : a*hmin+b)  (affine+relu monotone)
__global__ __launch_bounds__(256) void k_pass3(const short* __restrict__ hmax,
                                               const short* __restrict__ hmin,
                                               const float* __restrict__ gacc2,
                                               const float* __restrict__ g2,
                                               const float* __restrict__ be2,
                                               float* __restrict__ out) {
  __shared__ float lbn[128];
  int tid = threadIdx.x;
  bn_finalize(gacc2, g2, be2, lbn, tid);  // folded finalize2
  __syncthreads();
  int g = blockIdx.x * 256 + tid;  // 1.6M threads, 4 channels each
  int base = g * 4;
  int c4 = base & 63;
  short4 mx4 = *(const short4*)(hmax + base);
  short4 mn4 = *(const short4*)(hmin + base);
  float4 a4 = *(const float4*)(&lbn[c4]);
  float4 b4 = *(const float4*)(&lbn[64 + c4]);
  float4 o;
  o.x = fmaxf(a4.x >= 0.f ? fmaf(a4.x, bf2f(mx4.x), b4.x) : fmaf(a4.x, bf2f(mn4.x), b4.x), 0.f);
  o.y = fmaxf(a4.y >= 0.f ? fmaf(a4.y, bf2f(mx4.y), b4.y) : fmaf(a4.y, bf2f(mn4.y), b4.y), 0.f);
  o.z = fmaxf(a4.z >= 0.f ? fmaf(a4.z, bf2f(mx4.z), b4.z) : fmaf(a4.z, bf2f(mn4.z), b4.z), 0.f);
  o.w = fmaxf(a4.w >= 0.f ? fmaf(a4.w, bf2f(mx4.w), b4.w) : fmaf(a4.w, bf2f(mn4.w), b4.w), 0.f);
  *(float4*)(out + base) = o;
}

extern "C" void kernel_launch(void* const* d_in, const int* in_sizes, int n_in,
                              void* d_out, int out_size, void* d_ws, size_t ws_size,
                              hipStream_t stream) {
  const float* x   = (const float*)d_in[0];
  // d_in[1] = edge_row: structurally repeat(arange(N),16), unused
  const int*   ec  = (const int*)d_in[2];
  const float* W1  = (const float*)d_in[3];
  // d_in[4] = b1: cancels in BN, unused
  const float* g1  = (const float*)d_in[5];
  const float* be1 = (const float*)d_in[6];
  const float* W2  = (const float*)d_in[7];
  // d_in[8] = b2: cancels in BN, unused
  const float* g2  = (const float*)d_in[9];
  const float* be2 = (const float*)d_in[10];
  float* out = (float*)d_out;

  char* ws = (char*)d_ws;
  short* wp2s  = (short*)(ws + 16384);          // 8 KB packed W2
  float* gacc1 = (float*)(ws + 24576);          // 16 slots x 128 = 8 KB
  float* gacc2 = (float*)(ws + 32768);          // 8 KB (contiguous w/ gacc1)
  short* Ybf   = (short*)(ws + 98304);          // Y = X@Wd bf16: 12.8 MB
  short* Zb    = (short*)(ws + 98304 + 12800000);           // Z bf16: 12.8 MB
  short* hmax  = (short*)(ws + 98304 + 2 * 12800000);       // 12.8 MB
  short* hmin  = (short*)(ws + 98304 + 3 * 12800000);       // 12.8 MB
  unsigned char* Z8 = (unsigned char*)(ws + 98304 + 4 * 12800000);  // 6.4 MB

  hipLaunchKernelGGL(k_nodeYZ, dim3((NTILES + 3) / 4), dim3(256), 0, stream,
                     x, W1, W2, wp2s, gacc1, Ybf, Zb, Z8);
  hipLaunchKernelGGL(k_stats1, dim3(NCHUNK), dim3(256), 0, stream,
                     Z8, Ybf, ec, gacc1);
  hipLaunchKernelGGL(k_pass2, dim3(NCHUNK), dim3(256), 0, stream,
                     Zb, Ybf, ec, (const bf16x8*)wp2s, gacc1, g1, be1,
                     gacc2, hmax, hmin);
  hipLaunchKernelGGL(k_pass3, dim3(6250), dim3(256), 0, stream,
                     hmax, hmin, gacc2, g2, be2, out);
}